// Round 9
// baseline (284.901 us; speedup 1.0000x reference)
//
#include <hip/hip_runtime.h>
#include <hip/hip_bf16.h>

// Problem constants (fixed by reference)
#define B_ 16
#define L_ 24
#define N_ 256
#define E_ 4096
#define T_ (B_ * L_)   // 384 graphs

// All tensors float32. Output [B,L,N,64] f32 = 25.2 MB.
// X (LSTM h states, [T,N,64] f32) lives in d_out; k_graph overwrites its own
// tile in place. ws holds folded tables + pre-swizzled W_hh MFMA frags.
constexpr int WP    = 0;                   // P = W1a@W2b  (64x64)
constexpr int WRQ   = WP + 4096;           // RQ = W2a + Q (64x64), Q = W1b@W2b
constexpr int WRM   = WRQ + 4096;          // Q alone (for rare sel==0 correction)
constexpr int WBIAS = WRM + 4096;          // biasv [256][64]
constexpr int WALPHA= WBIAS + 16384;       // alpha[256]
constexpr int WBETA = WALPHA + 256;        // beta[256]
constexpr int WDINV = WBETA + 256;         // 1/max(cnt,1) [256]
constexpr int WSEL  = WDINV + 256;         // cnt>0 ? 1 : 0 [256]
constexpr int WSW   = WSEL + 256;          // sw0[256], sw1[256]
constexpr int WCNTF = WSW + 512;           // cnt as float [256]
constexpr int WCOLP = WCNTF + 256;         // 257 ints (CSR col ptr)
constexpr int WROWS = WCOLP + 260;         // 4096 ints
constexpr int WHFRAG= WROWS + 4096;        // 34820: W_hh bf16 MFMA frags, 2048 x 16B

using bf16x8 = __attribute__((ext_vector_type(8))) short;   // 8 bf16 (4 VGPRs)
using f32x4  = __attribute__((ext_vector_type(4))) float;   // MFMA C/D

__device__ __forceinline__ float sigm(float x) { return 1.f / (1.f + __expf(-x)); }
__device__ __forceinline__ float tanh_(float x) { return 2.f / (1.f + __expf(-2.f * x)) - 1.f; }
__device__ __forceinline__ float blo(unsigned u) { return __uint_as_float(u << 16); }
__device__ __forceinline__ float bhi(unsigned u) { return __uint_as_float(u & 0xffff0000u); }
__device__ __forceinline__ unsigned f2bf(float f) {   // RNE bf16 bits
    unsigned u = __float_as_uint(f);
    return (u + 0x7fffu + ((u >> 16) & 1u)) >> 16;
}

// ---- K1 fused prep: blk 0 = tables; blk 1..8 = P/RQ/Q; blk 9..12 = W frags
__global__ __launch_bounds__(256) void k_prep(
    const int* __restrict__ conn, const float* __restrict__ cw,
    const float* __restrict__ Wih, const float* __restrict__ embW,
    const float* __restrict__ embB, const float* __restrict__ bih,
    const float* __restrict__ bhh, const float* __restrict__ Whh,
    const float* __restrict__ m1W, const float* __restrict__ m1b,
    const float* __restrict__ m2W, const float* __restrict__ m2b,
    float* __restrict__ ws) {
    int t = threadIdx.x, blk = blockIdx.x;
    if (blk >= 9) {
        // W_hh -> bf16 B-fragments for mfma_f32_16x16x32_bf16.
        // frag p = ct*2 + ks; lane l holds B[k=ks*32+(l>>4)*8+j][n=l&15]
        //   = Whh[(ct*16 + (l&15))*64 + ks*32 + (l>>4)*8 + j], j=0..7.
        int idx = (blk - 9) * 256 + t;        // 0..1023
        for (int f = idx; f < 2048; f += 1024) {
            int p = f >> 6, l = f & 63;
            int ct = p >> 1, ks = p & 1;
            const float* src = Whh + (ct * 16 + (l & 15)) * 64 + ks * 32 + ((l >> 4) << 3);
            unsigned u[4];
            #pragma unroll
            for (int q = 0; q < 4; ++q)
                u[q] = f2bf(src[2 * q]) | (f2bf(src[2 * q + 1]) << 16);
            ((uint4*)(ws + WHFRAG))[f] = make_uint4(u[0], u[1], u[2], u[3]);
        }
        return;
    }
    if (blk > 0) {
        __shared__ float sB[64 * 64];   // W2b = m2W rows 64..127
        bool isP = blk <= 4;
        int kbase = ((blk - 1) & 3) * 16;
        #pragma unroll
        for (int i = 0; i < 16; ++i) sB[t + 256 * i] = m2W[64 * 64 + t + 256 * i];
        __syncthreads();
        int j = t & 63, kl = t >> 6;
        #pragma unroll
        for (int r = 0; r < 4; ++r) {
            int k = kbase + kl * 4 + r;
            const float* arow = m1W + (isP ? k : (64 + k)) * 64;
            float acc = 0.f;
            #pragma unroll
            for (int m = 0; m < 64; m += 4) {
                float4 a4 = *(const float4*)(arow + m);
                acc = fmaf(a4.x, sB[m * 64 + j], acc);
                acc = fmaf(a4.y, sB[(m + 1) * 64 + j], acc);
                acc = fmaf(a4.z, sB[(m + 2) * 64 + j], acc);
                acc = fmaf(a4.w, sB[(m + 3) * 64 + j], acc);
            }
            if (isP) {
                ws[WP + k * 64 + j] = acc;
            } else {
                ws[WRM + k * 64 + j] = acc;                       // Q
                ws[WRQ + k * 64 + j] = acc + m2W[k * 64 + j];     // W2a + Q
            }
        }
        return;
    }
    __shared__ int s_cnt[N_];
    __shared__ float s_sw0[N_], s_sw1[N_];
    __shared__ int s_pos[N_];
    __shared__ float sU[3 * 64];
    __shared__ int s_wsum[4];
    s_cnt[t] = 0; s_sw0[t] = 0.f; s_sw1[t] = 0.f;
    __syncthreads();
    for (int e = t; e < E_; e += 256) {
        int c = conn[E_ + e] & 255;
        atomicAdd(&s_cnt[c], 1);
        atomicAdd(&s_sw0[c], cw[2 * e]);
        atomicAdd(&s_sw1[c], cw[2 * e + 1]);
    }
    __syncthreads();
    int lane = t & 63, wv = t >> 6;
    int val = s_cnt[t];
    int inc = val;
    #pragma unroll
    for (int d = 1; d < 64; d <<= 1) {
        int y = __shfl_up(inc, d);
        if (lane >= d) inc += y;
    }
    if (lane == 63) s_wsum[wv] = inc;
    __syncthreads();
    int wadd = 0;
    for (int w = 0; w < wv; ++w) wadd += s_wsum[w];
    int excl = wadd + inc - val;
    int* colp = (int*)(ws + WCOLP);
    colp[t] = excl;
    if (t == 0) colp[N_] = E_;
    s_pos[t] = excl;
    int cnt = val;
    ws[WCNTF + t] = (float)cnt;
    ws[WDINV + t] = 1.f / (float)(cnt > 1 ? cnt : 1);
    ws[WSEL + t]  = cnt > 0 ? 1.f : 0.f;
    ws[WSW + t]        = s_sw0[t];
    ws[WSW + N_ + t]   = s_sw1[t];
    float a = 0.f, b = 0.f;
    #pragma unroll
    for (int i = 0; i < 16; ++i) {
        float w = Wih[t * 16 + i];
        a += w * embW[i];
        b += w * embB[i];
    }
    ws[WALPHA + t] = a;
    ws[WBETA + t]  = b + bih[t] + bhh[t];
    __syncthreads();   // all s_pos[] initialized before rows fill
    int* rows = (int*)(ws + WROWS);
    for (int e = t; e < E_; e += 256) {
        int c = conn[E_ + e] & 255;
        int p = atomicAdd(&s_pos[c], 1);
        rows[p] = conn[e] & 255;
    }
    if (t < 192) {
        int part = t >> 6, j = t & 63;
        float acc = 0.f;
        #pragma unroll 8
        for (int m = 0; m < 64; ++m) {
            float w = (part == 0) ? m1W[128 * 64 + m]
                    : (part == 1) ? m1W[129 * 64 + m] : m1b[m];
            acc = fmaf(w, m2W[(64 + m) * 64 + j], acc);
        }
        sU[part * 64 + j] = acc;
    }
    __syncthreads();
    {
        int j = t & 63;
        float u0 = sU[j], u1 = sU[64 + j], u2 = sU[128 + j];
        float b2j = m2b[j];
        int vb = t >> 6;
        #pragma unroll 8
        for (int i = 0; i < 64; ++i) {
            int v = vb + i * 4;
            int cv = s_cnt[v];
            float dv = 1.f / (float)(cv > 1 ? cv : 1);
            float bb = s_sw0[v] * u0 + s_sw1[v] * u1 + (float)cv * u2;
            ws[WBIAS + v * 64 + j] = dv * bb + b2j;
        }
    }
}

// ---------------- K2: MFMA LSTM. 1 wave = 16 sequences ---------------------
// gates[16 seq x 256] = (h_hi + h_lo) @ Whh^T via mfma_f32_16x16x32_bf16,
// h split into two bf16 fragments for ~f32 feedback precision. c stays f32.
__global__ __launch_bounds__(64, 1) void k_lstm(
    const float* __restrict__ aqi, const float* __restrict__ ws,
    float* __restrict__ xout) {
    __shared__ __align__(16) short sW[2048 * 8];      // 32 KB: W frags
    __shared__ __align__(16) short sHhi[16 * 72];     // h_hi tile (stride 72)
    __shared__ __align__(16) short sHlo[16 * 72];     // h_lo tile
    __shared__ float sX[24 * 16];                     // x[l][seq-row]
    int lane = threadIdx.x;
    int w = blockIdx.x;                 // tile 0..255
    int seq0 = w * 16;
    int b0 = seq0 >> 8, n0 = seq0 & 255;
    // stage W frags (global ws -> LDS), coalesced 16B/lane
    {
        const uint4* src = (const uint4*)(ws + WHFRAG);
        uint4* dst = (uint4*)sW;
        #pragma unroll
        for (int i = 0; i < 32; ++i) dst[lane + 64 * i] = src[lane + 64 * i];
    }
    // stage x: 16 seqs x 24 steps
    for (int i = lane; i < 384; i += 64) {
        int l = i >> 4, c = i & 15;
        sX[l * 16 + c] = aqi[(b0 * L_ + l) * N_ + n0 + c];
    }
    int c0 = lane & 15, quad = lane >> 4, q4 = quad * 4;
    // alpha/beta per col-tile (col = ct*16 + c0)
    float alF[16], beF[16];
    #pragma unroll
    for (int ct = 0; ct < 16; ++ct) {
        alF[ct] = ws[WALPHA + ct * 16 + c0];
        beF[ct] = ws[WBETA + ct * 16 + c0];
    }
    float cst[16];
    #pragma unroll
    for (int i = 0; i < 16; ++i) cst[i] = 0.f;
    bf16x8 hA[2][2] = {};
    for (int l = 0; l < L_; ++l) {
        float x4[4];
        #pragma unroll
        for (int r = 0; r < 4; ++r) x4[r] = sX[l * 16 + q4 + r];
        f32x4 acc[16];
        #pragma unroll
        for (int ct = 0; ct < 16; ++ct) {
            #pragma unroll
            for (int r = 0; r < 4; ++r)
                acc[ct][r] = fmaf(x4[r], alF[ct], beF[ct]);
        }
        if (l > 0) {
            #pragma unroll
            for (int ct = 0; ct < 16; ++ct) {
                #pragma unroll
                for (int ks = 0; ks < 2; ++ks) {
                    bf16x8 wb = *(const bf16x8*)&sW[((ct * 2 + ks) * 64 + lane) * 8];
                    acc[ct] = __builtin_amdgcn_mfma_f32_16x16x32_bf16(
                        hA[0][ks], wb, acc[ct], 0, 0, 0);
                    acc[ct] = __builtin_amdgcn_mfma_f32_16x16x32_bf16(
                        hA[1][ks], wb, acc[ct], 0, 0, 0);
                }
            }
        }
        // elementwise: gate tiles ct = gate*4 + ctc  (i,f,g,o gate order)
        float* orow = xout + ((size_t)(b0 * L_ + l) * N_ + n0) * 64;
        #pragma unroll
        for (int ctc = 0; ctc < 4; ++ctc) {
            #pragma unroll
            for (int r = 0; r < 4; ++r) {
                float iv = sigm(acc[ctc][r]);
                float fv = sigm(acc[4 + ctc][r]);
                float gv = tanh_(acc[8 + ctc][r]);
                float ov = sigm(acc[12 + ctc][r]);
                int ci = ctc * 4 + r;
                cst[ci] = fmaf(fv, cst[ci], iv * gv);
                float h = ov * tanh_(cst[ci]);
                orow[(q4 + r) * 64 + ctc * 16 + c0] = h;
                unsigned hb = f2bf(h);
                float hf = __uint_as_float(hb << 16);
                unsigned lb = f2bf(h - hf);
                sHhi[(q4 + r) * 72 + ctc * 16 + c0] = (short)hb;
                sHlo[(q4 + r) * 72 + ctc * 16 + c0] = (short)lb;
            }
        }
        // rebuild A-frags: A[m=lane&15][k=quad*8+j], k offset 32 for ks=1
        hA[0][0] = *(const bf16x8*)&sHhi[c0 * 72 + quad * 8];
        hA[0][1] = *(const bf16x8*)&sHhi[c0 * 72 + 32 + quad * 8];
        hA[1][0] = *(const bf16x8*)&sHlo[c0 * 72 + quad * 8];
        hA[1][1] = *(const bf16x8*)&sHlo[c0 * 72 + 32 + quad * 8];
    }
}

// ---------------- K4: per-graph GNN, S-space gather (frozen) ----------------
constexpr int XS = 66;  // bf16 LDS row stride: 33 words (odd -> full bank spread)

__global__ __launch_bounds__(256, 2) void k_graph(
    const float* __restrict__ ws, const float* __restrict__ m2W,
    float* __restrict__ out) {
    __shared__ __hip_bfloat16 Xl[N_ * XS];   // 33.8 KB
    int tg = blockIdx.x;
    int tid = threadIdx.x;
    const float4* src = (const float4*)(out + tg * (N_ * 64));
    #pragma unroll
    for (int it = 0; it < 16; ++it) {
        int idx = tid + it * 256;
        float4 d = src[idx];
        int node = idx >> 4, col = (idx & 15) * 4;
        __hip_bfloat162 p0 = __halves2bfloat162(__float2bfloat16(d.x), __float2bfloat16(d.y));
        __hip_bfloat162 p1 = __halves2bfloat162(__float2bfloat16(d.z), __float2bfloat16(d.w));
        unsigned* dst = (unsigned*)&Xl[node * XS + col];
        dst[0] = *(unsigned*)&p0;
        dst[1] = *(unsigned*)&p1;
    }
    __syncthreads();
    int v = tid;
    float S[64];
    #pragma unroll
    for (int k = 0; k < 64; ++k) S[k] = 0.f;
    {
        const int* colp = (const int*)(ws + WCOLP);
        const int* rows = (const int*)(ws + WROWS);
        int e1 = colp[v + 1];
        for (int e = colp[v]; e < e1; ++e) {
            int r = rows[e];
            const unsigned* xp = (const unsigned*)(Xl + r * XS);
            #pragma unroll
            for (int w = 0; w < 32; ++w) {
                unsigned u = xp[w];
                S[2 * w]     += blo(u);
                S[2 * w + 1] += bhi(u);
            }
        }
    }
    float dinv = ws[WDINV + v];
    float sel  = ws[WSEL + v];
    float acc[64];
    {
        const float* bv = ws + WBIAS + v * 64;
        #pragma unroll
        for (int j = 0; j < 64; j += 4) {
            float4 b4 = *(const float4*)(bv + j);
            acc[j] = b4.x; acc[j + 1] = b4.y; acc[j + 2] = b4.z; acc[j + 3] = b4.w;
        }
    }
    {
        const float* Pm = ws + WP;
        #pragma unroll 4
        for (int k = 0; k < 64; ++k) {
            float sv = dinv * S[k];
            const float* Pr = Pm + k * 64;
            #pragma unroll
            for (int j = 0; j < 64; j += 4) {
                float4 p = *(const float4*)(Pr + j);
                acc[j]     = fmaf(sv, p.x, acc[j]);
                acc[j + 1] = fmaf(sv, p.y, acc[j + 1]);
                acc[j + 2] = fmaf(sv, p.z, acc[j + 2]);
                acc[j + 3] = fmaf(sv, p.w, acc[j + 3]);
            }
        }
    }
    {
        const unsigned* xrow = (const unsigned*)(Xl + v * XS);
        const float* Mm = ws + WRQ;
        #pragma unroll 4
        for (int kk = 0; kk < 32; ++kk) {
            unsigned u = xrow[kk];
            float x0 = blo(u), x1 = bhi(u);
            const float* M0 = Mm + (2 * kk) * 64;
            const float* M1 = M0 + 64;
            #pragma unroll
            for (int j = 0; j < 64; j += 4) {
                float4 m0 = *(const float4*)(M0 + j);
                float4 m1 = *(const float4*)(M1 + j);
                acc[j]     = fmaf(x0, m0.x, fmaf(x1, m1.x, acc[j]));
                acc[j + 1] = fmaf(x0, m0.y, fmaf(x1, m1.y, acc[j + 1]));
                acc[j + 2] = fmaf(x0, m0.z, fmaf(x1, m1.z, acc[j + 2]));
                acc[j + 3] = fmaf(x0, m0.w, fmaf(x1, m1.w, acc[j + 3]));
            }
        }
    }
    if (sel < 0.5f) {
        const unsigned* xrow = (const unsigned*)(Xl + v * XS);
        const float* Qm = ws + WRM;
        for (int kk = 0; kk < 32; ++kk) {
            unsigned u = xrow[kk];
            float x0 = blo(u), x1 = bhi(u);
            const float* Q0 = Qm + (2 * kk) * 64;
            const float* Q1 = Q0 + 64;
            for (int j = 0; j < 64; ++j)
                acc[j] -= x0 * Q0[j] + x1 * Q1[j];
        }
    }
    float* og = out + (tg * N_ + v) * 64;
    #pragma unroll
    for (int j = 0; j < 64; j += 4) {
        *(float4*)(og + j) = make_float4(acc[j], acc[j + 1], acc[j + 2], acc[j + 3]);
    }
}

extern "C" void kernel_launch(void* const* d_in, const int* in_sizes, int n_in,
                              void* d_out, int out_size, void* d_ws, size_t ws_size,
                              hipStream_t stream) {
    const float* aqi  = (const float*)d_in[0];
    const int*   conn = (const int*)d_in[1];
    const float* cw   = (const float*)d_in[2];
    const float* embW = (const float*)d_in[3];
    const float* embB = (const float*)d_in[4];
    const float* Wih  = (const float*)d_in[5];
    const float* Whh  = (const float*)d_in[6];
    const float* bih  = (const float*)d_in[7];
    const float* bhh  = (const float*)d_in[8];
    const float* m1W  = (const float*)d_in[9];
    const float* m1b  = (const float*)d_in[10];
    const float* m2W  = (const float*)d_in[11];
    const float* m2b  = (const float*)d_in[12];
    float* ws  = (float*)d_ws;
    float* out = (float*)d_out;

    k_prep<<<dim3(13), dim3(256), 0, stream>>>(conn, cw, Wih, embW, embB, bih, bhh,
                                               Whh, m1W, m1b, m2W, m2b, ws);
    k_lstm<<<dim3(256), dim3(64), 0, stream>>>(aqi, ws, out);
    k_graph<<<dim3(T_), dim3(256), 0, stream>>>(ws, m2W, out);
}

// Round 10
// 213.418 us; speedup vs baseline: 1.3349x; 1.3349x over previous
//
#include <hip/hip_runtime.h>
#include <hip/hip_bf16.h>

// Problem constants (fixed by reference)
#define B_ 16
#define L_ 24
#define N_ 256
#define E_ 4096
#define T_ (B_ * L_)   // 384 graphs

// All tensors float32. Output [B,L,N,64] f32 = 25.2 MB.
// X (LSTM h states, [T,N,64] f32) lives in d_out; k_graph overwrites its own
// tile in place. ws holds folded tables + pre-swizzled W_hh MFMA frags.
constexpr int WP    = 0;                   // P = W1a@W2b  (64x64)
constexpr int WRQ   = WP + 4096;           // RQ = W2a + Q (64x64), Q = W1b@W2b
constexpr int WRM   = WRQ + 4096;          // Q alone (for rare sel==0 correction)
constexpr int WBIAS = WRM + 4096;          // biasv [256][64]
constexpr int WALPHA= WBIAS + 16384;       // alpha[256]
constexpr int WBETA = WALPHA + 256;        // beta[256]
constexpr int WDINV = WBETA + 256;         // 1/max(cnt,1) [256]
constexpr int WSEL  = WDINV + 256;         // cnt>0 ? 1 : 0 [256]
constexpr int WSW   = WSEL + 256;          // sw0[256], sw1[256]
constexpr int WCNTF = WSW + 512;           // cnt as float [256]
constexpr int WCOLP = WCNTF + 256;         // 257 ints (CSR col ptr)
constexpr int WROWS = WCOLP + 260;         // 4096 ints
constexpr int WHFRAG= WROWS + 4096;        // W_hh bf16 MFMA frags, 2048 x 16B

using bf16x8 = __attribute__((ext_vector_type(8))) short;   // 8 bf16 (4 VGPRs)
using f32x4  = __attribute__((ext_vector_type(4))) float;   // MFMA C/D

__device__ __forceinline__ float sigm(float x) { return 1.f / (1.f + __expf(-x)); }
__device__ __forceinline__ float tanh_(float x) { return 2.f / (1.f + __expf(-2.f * x)) - 1.f; }
__device__ __forceinline__ float blo(unsigned u) { return __uint_as_float(u << 16); }
__device__ __forceinline__ float bhi(unsigned u) { return __uint_as_float(u & 0xffff0000u); }
__device__ __forceinline__ unsigned f2bf(float f) {   // RNE bf16 bits
    unsigned u = __float_as_uint(f);
    return (u + 0x7fffu + ((u >> 16) & 1u)) >> 16;
}

// ---- K1 fused prep: blk 0 = tables; blk 1..8 = P/RQ/Q; blk 9..12 = W frags
__global__ __launch_bounds__(256) void k_prep(
    const int* __restrict__ conn, const float* __restrict__ cw,
    const float* __restrict__ Wih, const float* __restrict__ embW,
    const float* __restrict__ embB, const float* __restrict__ bih,
    const float* __restrict__ bhh, const float* __restrict__ Whh,
    const float* __restrict__ m1W, const float* __restrict__ m1b,
    const float* __restrict__ m2W, const float* __restrict__ m2b,
    float* __restrict__ ws) {
    int t = threadIdx.x, blk = blockIdx.x;
    if (blk >= 9) {
        // W_hh -> bf16 B-fragments for mfma_f32_16x16x32_bf16.
        // frag p = ct*2 + ks; lane l holds B[k=ks*32+(l>>4)*8+j][n=l&15]
        //   = Whh[(ct*16 + (l&15))*64 + ks*32 + (l>>4)*8 + j], j=0..7.
        int idx = (blk - 9) * 256 + t;        // 0..1023
        for (int f = idx; f < 2048; f += 1024) {
            int p = f >> 6, l = f & 63;
            int ct = p >> 1, ks = p & 1;
            const float* src = Whh + (ct * 16 + (l & 15)) * 64 + ks * 32 + ((l >> 4) << 3);
            unsigned u[4];
            #pragma unroll
            for (int q = 0; q < 4; ++q)
                u[q] = f2bf(src[2 * q]) | (f2bf(src[2 * q + 1]) << 16);
            ((uint4*)(ws + WHFRAG))[f] = make_uint4(u[0], u[1], u[2], u[3]);
        }
        return;
    }
    if (blk > 0) {
        __shared__ float sB[64 * 64];   // W2b = m2W rows 64..127
        bool isP = blk <= 4;
        int kbase = ((blk - 1) & 3) * 16;
        #pragma unroll
        for (int i = 0; i < 16; ++i) sB[t + 256 * i] = m2W[64 * 64 + t + 256 * i];
        __syncthreads();
        int j = t & 63, kl = t >> 6;
        #pragma unroll
        for (int r = 0; r < 4; ++r) {
            int k = kbase + kl * 4 + r;
            const float* arow = m1W + (isP ? k : (64 + k)) * 64;
            float acc = 0.f;
            #pragma unroll
            for (int m = 0; m < 64; m += 4) {
                float4 a4 = *(const float4*)(arow + m);
                acc = fmaf(a4.x, sB[m * 64 + j], acc);
                acc = fmaf(a4.y, sB[(m + 1) * 64 + j], acc);
                acc = fmaf(a4.z, sB[(m + 2) * 64 + j], acc);
                acc = fmaf(a4.w, sB[(m + 3) * 64 + j], acc);
            }
            if (isP) {
                ws[WP + k * 64 + j] = acc;
            } else {
                ws[WRM + k * 64 + j] = acc;                       // Q
                ws[WRQ + k * 64 + j] = acc + m2W[k * 64 + j];     // W2a + Q
            }
        }
        return;
    }
    __shared__ int s_cnt[N_];
    __shared__ float s_sw0[N_], s_sw1[N_];
    __shared__ int s_pos[N_];
    __shared__ float sU[3 * 64];
    __shared__ int s_wsum[4];
    s_cnt[t] = 0; s_sw0[t] = 0.f; s_sw1[t] = 0.f;
    __syncthreads();
    for (int e = t; e < E_; e += 256) {
        int c = conn[E_ + e] & 255;
        atomicAdd(&s_cnt[c], 1);
        atomicAdd(&s_sw0[c], cw[2 * e]);
        atomicAdd(&s_sw1[c], cw[2 * e + 1]);
    }
    __syncthreads();
    int lane = t & 63, wv = t >> 6;
    int val = s_cnt[t];
    int inc = val;
    #pragma unroll
    for (int d = 1; d < 64; d <<= 1) {
        int y = __shfl_up(inc, d);
        if (lane >= d) inc += y;
    }
    if (lane == 63) s_wsum[wv] = inc;
    __syncthreads();
    int wadd = 0;
    for (int w = 0; w < wv; ++w) wadd += s_wsum[w];
    int excl = wadd + inc - val;
    int* colp = (int*)(ws + WCOLP);
    colp[t] = excl;
    if (t == 0) colp[N_] = E_;
    s_pos[t] = excl;
    int cnt = val;
    ws[WCNTF + t] = (float)cnt;
    ws[WDINV + t] = 1.f / (float)(cnt > 1 ? cnt : 1);
    ws[WSEL + t]  = cnt > 0 ? 1.f : 0.f;
    ws[WSW + t]        = s_sw0[t];
    ws[WSW + N_ + t]   = s_sw1[t];
    float a = 0.f, b = 0.f;
    #pragma unroll
    for (int i = 0; i < 16; ++i) {
        float w = Wih[t * 16 + i];
        a += w * embW[i];
        b += w * embB[i];
    }
    ws[WALPHA + t] = a;
    ws[WBETA + t]  = b + bih[t] + bhh[t];
    __syncthreads();   // all s_pos[] initialized before rows fill
    int* rows = (int*)(ws + WROWS);
    for (int e = t; e < E_; e += 256) {
        int c = conn[E_ + e] & 255;
        int p = atomicAdd(&s_pos[c], 1);
        rows[p] = conn[e] & 255;
    }
    if (t < 192) {
        int part = t >> 6, j = t & 63;
        float acc = 0.f;
        #pragma unroll 8
        for (int m = 0; m < 64; ++m) {
            float w = (part == 0) ? m1W[128 * 64 + m]
                    : (part == 1) ? m1W[129 * 64 + m] : m1b[m];
            acc = fmaf(w, m2W[(64 + m) * 64 + j], acc);
        }
        sU[part * 64 + j] = acc;
    }
    __syncthreads();
    {
        int j = t & 63;
        float u0 = sU[j], u1 = sU[64 + j], u2 = sU[128 + j];
        float b2j = m2b[j];
        int vb = t >> 6;
        #pragma unroll 8
        for (int i = 0; i < 64; ++i) {
            int v = vb + i * 4;
            int cv = s_cnt[v];
            float dv = 1.f / (float)(cv > 1 ? cv : 1);
            float bb = s_sw0[v] * u0 + s_sw1[v] * u1 + (float)cv * u2;
            ws[WBIAS + v * 64 + j] = dv * bb + b2j;
        }
    }
}

// ------- K2: MFMA LSTM. block = 16 seqs, 4 waves split the 16 col-tiles -----
// Wave w owns hidden cols [16w,16w+16): gate tiles ct = {w, 4+w, 8+w, 12+w}.
// h tile (hi+lo bf16) double-buffered in LDS; one __syncthreads per step.
constexpr int HS = 72;   // h tile row stride in shorts (16B-aligned rows)

__global__ __launch_bounds__(256, 1) void k_lstm(
    const float* __restrict__ aqi, const float* __restrict__ ws,
    float* __restrict__ xout) {
    __shared__ __align__(16) short sW[2048 * 8];        // 32 KB: W frags
    __shared__ __align__(16) short sHhi[2][16 * HS];    // h_hi, 2 step-parity bufs
    __shared__ __align__(16) short sHlo[2][16 * HS];
    __shared__ float sX[24 * 16];                       // x[l][seq-row]
    int t = threadIdx.x;
    int w = t >> 6, lane = t & 63;
    int seq0 = blockIdx.x * 16;
    int b0 = seq0 >> 8, n0 = seq0 & 255;
    // stage W frags (coalesced 16B/lane x 256 threads x 8 iters)
    {
        const uint4* src = (const uint4*)(ws + WHFRAG);
        uint4* dst = (uint4*)sW;
        #pragma unroll
        for (int i = 0; i < 8; ++i) dst[t + 256 * i] = src[t + 256 * i];
    }
    // stage x: 16 seqs x 24 steps
    for (int i = t; i < 384; i += 256) {
        int l = i >> 4, c = i & 15;
        sX[l * 16 + c] = aqi[(b0 * L_ + l) * N_ + n0 + c];
    }
    int c0 = lane & 15, quad = lane >> 4, q4 = quad * 4, q8 = quad * 8;
    // alpha/beta for this wave's 4 gate tiles (col = (4g+w)*16 + c0)
    float alF[4], beF[4];
    #pragma unroll
    for (int g = 0; g < 4; ++g) {
        alF[g] = ws[WALPHA + (4 * g + w) * 16 + c0];
        beF[g] = ws[WBETA  + (4 * g + w) * 16 + c0];
    }
    float cst[4] = {0.f, 0.f, 0.f, 0.f};
    bf16x8 hA[2][2] = {};
    __syncthreads();
    for (int l = 0; l < L_; ++l) {
        int buf = l & 1;
        f32x4 acc[4];
        #pragma unroll
        for (int g = 0; g < 4; ++g) {
            #pragma unroll
            for (int r = 0; r < 4; ++r)
                acc[g][r] = fmaf(sX[l * 16 + q4 + r], alF[g], beF[g]);
        }
        if (l > 0) {
            #pragma unroll
            for (int g = 0; g < 4; ++g) {
                int ct = 4 * g + w;
                #pragma unroll
                for (int ks = 0; ks < 2; ++ks) {
                    bf16x8 wb = *(const bf16x8*)&sW[((ct * 2 + ks) * 64 + lane) * 8];
                    acc[g] = __builtin_amdgcn_mfma_f32_16x16x32_bf16(
                        hA[0][ks], wb, acc[g], 0, 0, 0);
                    acc[g] = __builtin_amdgcn_mfma_f32_16x16x32_bf16(
                        hA[1][ks], wb, acc[g], 0, 0, 0);
                }
            }
        }
        // elementwise for this wave's 16 cols x 16 seqs (i,f,g,o gate order)
        float* orow = xout + ((size_t)(b0 * L_ + l) * N_ + n0) * 64;
        #pragma unroll
        for (int r = 0; r < 4; ++r) {
            float iv = sigm(acc[0][r]);
            float fv = sigm(acc[1][r]);
            float gv = tanh_(acc[2][r]);
            float ov = sigm(acc[3][r]);
            cst[r] = fmaf(fv, cst[r], iv * gv);
            float h = ov * tanh_(cst[r]);
            orow[(q4 + r) * 64 + w * 16 + c0] = h;
            unsigned hb = f2bf(h);
            float hf = __uint_as_float(hb << 16);
            unsigned lb = f2bf(h - hf);
            sHhi[buf][(q4 + r) * HS + w * 16 + c0] = (short)hb;
            sHlo[buf][(q4 + r) * HS + w * 16 + c0] = (short)lb;
        }
        __syncthreads();   // h tile complete; frag reads below are safe
        // rebuild A-frags: A[m=c0][k=q8+j (+32 for ks=1)]
        hA[0][0] = *(const bf16x8*)&sHhi[buf][c0 * HS + q8];
        hA[0][1] = *(const bf16x8*)&sHhi[buf][c0 * HS + 32 + q8];
        hA[1][0] = *(const bf16x8*)&sHlo[buf][c0 * HS + q8];
        hA[1][1] = *(const bf16x8*)&sHlo[buf][c0 * HS + 32 + q8];
    }
}

// ---------------- K4: per-graph GNN, S-space gather (frozen) ----------------
constexpr int XS = 66;  // bf16 LDS row stride: 33 words (odd -> full bank spread)

__global__ __launch_bounds__(256, 2) void k_graph(
    const float* __restrict__ ws, const float* __restrict__ m2W,
    float* __restrict__ out) {
    __shared__ __hip_bfloat16 Xl[N_ * XS];   // 33.8 KB
    int tg = blockIdx.x;
    int tid = threadIdx.x;
    const float4* src = (const float4*)(out + tg * (N_ * 64));
    #pragma unroll
    for (int it = 0; it < 16; ++it) {
        int idx = tid + it * 256;
        float4 d = src[idx];
        int node = idx >> 4, col = (idx & 15) * 4;
        __hip_bfloat162 p0 = __halves2bfloat162(__float2bfloat16(d.x), __float2bfloat16(d.y));
        __hip_bfloat162 p1 = __halves2bfloat162(__float2bfloat16(d.z), __float2bfloat16(d.w));
        unsigned* dst = (unsigned*)&Xl[node * XS + col];
        dst[0] = *(unsigned*)&p0;
        dst[1] = *(unsigned*)&p1;
    }
    __syncthreads();
    int v = tid;
    float S[64];
    #pragma unroll
    for (int k = 0; k < 64; ++k) S[k] = 0.f;
    {
        const int* colp = (const int*)(ws + WCOLP);
        const int* rows = (const int*)(ws + WROWS);
        int e1 = colp[v + 1];
        for (int e = colp[v]; e < e1; ++e) {
            int r = rows[e];
            const unsigned* xp = (const unsigned*)(Xl + r * XS);
            #pragma unroll
            for (int w = 0; w < 32; ++w) {
                unsigned u = xp[w];
                S[2 * w]     += blo(u);
                S[2 * w + 1] += bhi(u);
            }
        }
    }
    float dinv = ws[WDINV + v];
    float sel  = ws[WSEL + v];
    float acc[64];
    {
        const float* bv = ws + WBIAS + v * 64;
        #pragma unroll
        for (int j = 0; j < 64; j += 4) {
            float4 b4 = *(const float4*)(bv + j);
            acc[j] = b4.x; acc[j + 1] = b4.y; acc[j + 2] = b4.z; acc[j + 3] = b4.w;
        }
    }
    {
        const float* Pm = ws + WP;
        #pragma unroll 4
        for (int k = 0; k < 64; ++k) {
            float sv = dinv * S[k];
            const float* Pr = Pm + k * 64;
            #pragma unroll
            for (int j = 0; j < 64; j += 4) {
                float4 p = *(const float4*)(Pr + j);
                acc[j]     = fmaf(sv, p.x, acc[j]);
                acc[j + 1] = fmaf(sv, p.y, acc[j + 1]);
                acc[j + 2] = fmaf(sv, p.z, acc[j + 2]);
                acc[j + 3] = fmaf(sv, p.w, acc[j + 3]);
            }
        }
    }
    {
        const unsigned* xrow = (const unsigned*)(Xl + v * XS);
        const float* Mm = ws + WRQ;
        #pragma unroll 4
        for (int kk = 0; kk < 32; ++kk) {
            unsigned u = xrow[kk];
            float x0 = blo(u), x1 = bhi(u);
            const float* M0 = Mm + (2 * kk) * 64;
            const float* M1 = M0 + 64;
            #pragma unroll
            for (int j = 0; j < 64; j += 4) {
                float4 m0 = *(const float4*)(M0 + j);
                float4 m1 = *(const float4*)(M1 + j);
                acc[j]     = fmaf(x0, m0.x, fmaf(x1, m1.x, acc[j]));
                acc[j + 1] = fmaf(x0, m0.y, fmaf(x1, m1.y, acc[j + 1]));
                acc[j + 2] = fmaf(x0, m0.z, fmaf(x1, m1.z, acc[j + 2]));
                acc[j + 3] = fmaf(x0, m0.w, fmaf(x1, m1.w, acc[j + 3]));
            }
        }
    }
    if (sel < 0.5f) {
        const unsigned* xrow = (const unsigned*)(Xl + v * XS);
        const float* Qm = ws + WRM;
        for (int kk = 0; kk < 32; ++kk) {
            unsigned u = xrow[kk];
            float x0 = blo(u), x1 = bhi(u);
            const float* Q0 = Qm + (2 * kk) * 64;
            const float* Q1 = Q0 + 64;
            for (int j = 0; j < 64; ++j)
                acc[j] -= x0 * Q0[j] + x1 * Q1[j];
        }
    }
    float* og = out + (tg * N_ + v) * 64;
    #pragma unroll
    for (int j = 0; j < 64; j += 4) {
        *(float4*)(og + j) = make_float4(acc[j], acc[j + 1], acc[j + 2], acc[j + 3]);
    }
}

extern "C" void kernel_launch(void* const* d_in, const int* in_sizes, int n_in,
                              void* d_out, int out_size, void* d_ws, size_t ws_size,
                              hipStream_t stream) {
    const float* aqi  = (const float*)d_in[0];
    const int*   conn = (const int*)d_in[1];
    const float* cw   = (const float*)d_in[2];
    const float* embW = (const float*)d_in[3];
    const float* embB = (const float*)d_in[4];
    const float* Wih  = (const float*)d_in[5];
    const float* Whh  = (const float*)d_in[6];
    const float* bih  = (const float*)d_in[7];
    const float* bhh  = (const float*)d_in[8];
    const float* m1W  = (const float*)d_in[9];
    const float* m1b  = (const float*)d_in[10];
    const float* m2W  = (const float*)d_in[11];
    const float* m2b  = (const float*)d_in[12];
    float* ws  = (float*)d_ws;
    float* out = (float*)d_out;

    k_prep<<<dim3(13), dim3(256), 0, stream>>>(conn, cw, Wih, embW, embB, bih, bhh,
                                               Whh, m1W, m1b, m2W, m2b, ws);
    k_lstm<<<dim3(256), dim3(256), 0, stream>>>(aqi, ws, out);
    k_graph<<<dim3(T_), dim3(256), 0, stream>>>(ws, m2W, out);
}